// Round 10
// baseline (267.757 us; speedup 1.0000x reference)
//
#include <hip/hip_runtime.h>
#include <hip/hip_fp16.h>

#define IRR    56
#define EF     48
#define WN     832
#define NEDGE  160000
#define NNODE  8000
#define NT     512                // 8 waves: crew0 (waves 0-3) flavor 0, crew1 (waves 4-7) flavor 1
#define TE2    64                 // edges per task
#define NTASK  (NEDGE / TE2)      // 2500
#define GRID   512                // persistent: 2 blocks/CU, ~5 tasks each
#define STRIDE 512

#define INV_SQRT3 0.5773502691896258f
#define INV_SQRT2 0.7071067811865476f
#define A_SCAL    0.22360679774997896f   // 1/sqrt(20)
#define A_VEC     0.20412414523193154f   // 1/sqrt(24)

typedef __bf16 bf16x8 __attribute__((ext_vector_type(8)));
typedef float  f32x4  __attribute__((ext_vector_type(4)));
typedef unsigned short u16x8 __attribute__((ext_vector_type(8)));
typedef unsigned short u16x4 __attribute__((ext_vector_type(4)));

__device__ __forceinline__ unsigned short f2bf(float f) {
    unsigned int u = __builtin_bit_cast(unsigned int, f);
    u += 0x7FFFu + ((u >> 16) & 1u);          // RNE
    return (unsigned short)(u >> 16);
}

// ---- setup: W1T [n][64] + W2L lane-major fragment layout + src histogram ----
// W2L[o]: o = ((i*2+f)*64 + l)*8 + j ; lane l=(q*16+m); value = W2[k= f*32+q*8+j][n= i*16+m]
__global__ void k_setup(const float* __restrict__ w1, const float* __restrict__ b1,
                        const float* __restrict__ w2, const float* __restrict__ b2,
                        unsigned short* __restrict__ W1T, unsigned short* __restrict__ W2L,
                        const int* __restrict__ edge_index, int* __restrict__ hist)
{
    int o = blockIdx.x * 256 + threadIdx.x;
    if (o < 64 * 832) {                       // 53248 elements, coalesced over n
        int k = o / 832;
        int n = o - k * 832;
        float v = (k < EF) ? w2[k * WN + n] : ((k == EF) ? b2[n] : 0.f);
        int i = n >> 4, mm = n & 15;
        int f = k >> 5, q = (k >> 3) & 3, j = k & 7;
        int o2 = (((i * 2 + f) * 64) + (q * 16 + mm)) * 8 + j;
        W2L[o2] = f2bf(v);
    }
    if (o < EF * EF) { int k = o / EF, n = o - k * EF; W1T[n * 64 + k] = f2bf(w1[o]); }
    if (o < EF * 16) { int n = o >> 4, kk = EF + (o & 15); W1T[n * 64 + kk] = (kk == EF) ? f2bf(b1[n]) : (unsigned short)0; }
    if (o < NEDGE) atomicAdd(&hist[edge_index[o]], 1);   // src counts
}

// Champion (82us) structure made persistent + T14 cross-task register prefetch:
// during GEMM2 of task t, each lane issues the full front-end load set of task
// t+STRIDE (indices, hist->inv, edge_sh, gather slice, crew0 edge_attr) into
// registers; next __syncthreads drains them; committed to LDS at loop top.
__global__ __launch_bounds__(NT, 4) void tp_fused(
    const float* __restrict__ node_attr,
    const float* __restrict__ edge_attr,
    const float* __restrict__ edge_sh,
    const int*   __restrict__ edge_index,
    const int*   __restrict__ hist,
    const unsigned short* __restrict__ W1T,
    const unsigned short* __restrict__ W2L,
    float* __restrict__ out)
{
    __shared__ __align__(16) float sG[TE2 * 56];               // 14336 B gathered node rows
    __shared__ __align__(16) unsigned short sH[TE2 * 72];      // 9216 B  H (bf16), stride 72
    __shared__ __align__(16) float sF0[TE2 * 61];              // 15616 B flavor-0 features
    __shared__ __align__(16) float sF1[TE2 * 61];              // 15616 B flavor-1 features
    __shared__ __align__(16) float sO[TE2 * IRR];              // 14336 B output staging
    __shared__ int   sSrc[TE2];
    __shared__ float sInv[TE2];
    // total ~69.6 KB -> 2 blocks/CU

    const int tid   = threadIdx.x;
    const int lane  = tid & 63;
    const int wv    = tid >> 6;                  // 0..7
    const int half  = wv >> 2;                   // crew: 0 -> flavor 0, 1 -> flavor 1
    const int m     = lane & 15;
    const int quad  = lane >> 4;
    const int em    = (wv & 3) * 16 + m;         // block-local edge owned by this lane (per crew)

    // ---- W1T fragments hoisted (task-invariant, 24 VGPR) ----
    bf16x8 a00 = __builtin_bit_cast(bf16x8, *(const u16x8*)&W1T[( 0 + m) * 64 + quad * 8]);
    bf16x8 a01 = __builtin_bit_cast(bf16x8, *(const u16x8*)&W1T[( 0 + m) * 64 + 32 + quad * 8]);
    bf16x8 a10 = __builtin_bit_cast(bf16x8, *(const u16x8*)&W1T[(16 + m) * 64 + quad * 8]);
    bf16x8 a11 = __builtin_bit_cast(bf16x8, *(const u16x8*)&W1T[(16 + m) * 64 + 32 + quad * 8]);
    bf16x8 a20 = __builtin_bit_cast(bf16x8, *(const u16x8*)&W1T[(32 + m) * 64 + quad * 8]);
    bf16x8 a21 = __builtin_bit_cast(bf16x8, *(const u16x8*)&W1T[(32 + m) * 64 + 32 + quad * 8]);

    // ---- prefetch state (registers) ----
    float4 pg0, pg1;                 // gather slice (this lane's columns of node row em)
    float4 pa0, pa1, pa2, pa3;       // edge_attr (crew0)
    float4 psh;                      // edge_sh
    int    psrc; float pinv;

    auto PREFETCH = [&](int t) {
        const int pe = t * TE2 + em;
        psrc = edge_index[pe];
        const int pdst = edge_index[NEDGE + pe];
        psh  = *(const float4*)&edge_sh[(size_t)pe * 4];
        pinv = 1.0f / fmaxf((float)hist[psrc], 1.0f);            // chained after psrc
        const float* nrow = node_attr + (size_t)pdst * IRR;      // chained after pdst
        if (half == 0) {
            pg0 = *(const float4*)(nrow + quad * 4);
            pg1 = *(const float4*)(nrow + (quad + 4) * 4);
            const float* arow = edge_attr + (size_t)pe * EF;
            pa0 = *(const float4*)(arow + quad * 8);
            pa1 = *(const float4*)(arow + quad * 8 + 4);
            if (quad < 2) {
                pa2 = *(const float4*)(arow + 32 + quad * 8);
                pa3 = *(const float4*)(arow + 32 + quad * 8 + 4);
            } else {
                pa2 = float4{0.f, 0.f, 0.f, 0.f};
                pa3 = float4{0.f, 0.f, 0.f, 0.f};
            }
        } else {
            pg0 = *(const float4*)(nrow + (quad + 8) * 4);
            int c = (quad < 2) ? (12 + quad) : 13;               // quad>=2: redundant col 13
            pg1 = *(const float4*)(nrow + c * 4);
        }
    };

    PREFETCH(blockIdx.x);            // prologue prefetch for first task

    for (int task = blockIdx.x; task < NTASK; task += STRIDE) {
        __syncthreads();   // (P) prev LDS reads done; prefetched loads drained

        // ---- commit prefetched state ----
        const float s0 = psh.x, sx = psh.y, sy = psh.z, sz = psh.w;
        {
            float* g = sG + em * 56;
            if (half == 0) {
                *(float4*)(g + quad * 4)       = pg0;
                *(float4*)(g + (quad + 4) * 4) = pg1;
                if (quad == 0) { sSrc[em] = psrc; sInv[em] = pinv; }
            } else {
                *(float4*)(g + (quad + 8) * 4) = pg0;
                if (quad < 2) *(float4*)(g + (12 + quad) * 4) = pg1;
            }
        }
        // crew0: edge_attr regs -> bf16 (register-only, do before PREFETCH overwrites)
        bf16x8 hb0, hb1;
        if (half == 0) {
            float av0[8] = {pa0.x,pa0.y,pa0.z,pa0.w, pa1.x,pa1.y,pa1.z,pa1.w};
            float av1[8] = {pa2.x,pa2.y,pa2.z,pa2.w, pa3.x,pa3.y,pa3.z,pa3.w};
            if (quad == 2) av1[0] = 1.f;           // bias row k=48 (quad>=2 loaded zeros)
            u16x8 ub0, ub1;
            #pragma unroll
            for (int j = 0; j < 8; j++) { ub0[j] = f2bf(av0[j]); ub1[j] = f2bf(av1[j]); }
            hb0 = __builtin_bit_cast(bf16x8, ub0);
            hb1 = __builtin_bit_cast(bf16x8, ub1);
        }

        __syncthreads();   // (B) sG complete

        // ---- F features in f32 (wave-local rows) ----
        {
            const float* x = sG + em * 56;
            const float c0S = s0 * A_SCAL;
            const float c0V = s0 * A_VEC;
            const float cD3 = INV_SQRT3 * A_SCAL;
            const float cC2 = INV_SQRT2 * A_VEC;
            if (half == 0) {
                float* F = sF0 + em * 61;
                #pragma unroll
                for (int t = 0; t < 4; t++) {
                    int u = quad * 4 + t;
                    float x0e = x[u];
                    F[u]      = x0e * c0S;    // wA0
                    F[20 + u] = x0e * A_VEC;  // wA1
                }
                {
                    int u = quad;
                    float aa0 = x[16 + u*3], aa1 = x[16 + u*3 + 1], aa2 = x[16 + u*3 + 2]; // x1o
                    float bb0 = x[28 + u*3], bb1 = x[28 + u*3 + 1], bb2 = x[28 + u*3 + 2]; // x1e
                    F[16 + u] = (aa0*sx + aa1*sy + aa2*sz) * cD3;     // wB0 dot_b
                    F[36 + u*3 + 0] = aa0 * c0V;                      // wB1
                    F[36 + u*3 + 1] = aa1 * c0V;
                    F[36 + u*3 + 2] = aa2 * c0V;
                    F[48 + u*3 + 0] = (bb1*sz - bb2*sy) * cC2;        // wC1 cross(x1e,s1)
                    F[48 + u*3 + 1] = (bb2*sx - bb0*sz) * cC2;
                    F[48 + u*3 + 2] = (bb0*sy - bb1*sx) * cC2;
                }
            } else {
                float* F = sF1 + em * 61;
                {
                    int u = quad;
                    float aa0 = x[16 + u*3], aa1 = x[16 + u*3 + 1], aa2 = x[16 + u*3 + 2]; // x1o
                    float bb0 = x[28 + u*3], bb1 = x[28 + u*3 + 1], bb2 = x[28 + u*3 + 2]; // x1e
                    F[u*3 + 0]      = (aa1*sz - aa2*sy) * cC2;        // wB1e cross(x1o,s1)
                    F[u*3 + 1]      = (aa2*sx - aa0*sz) * cC2;
                    F[u*3 + 2]      = (aa0*sy - aa1*sx) * cC2;
                    F[12 + u*3 + 0] = bb0 * c0V;                      // wC1e
                    F[12 + u*3 + 1] = bb1 * c0V;
                    F[12 + u*3 + 2] = bb2 * c0V;
                    F[40 + u]       = (bb0*sx + bb1*sy + bb2*sz) * cD3; // wC0o dot_c
                }
                #pragma unroll
                for (int t = 0; t < 4; t++) {
                    int u = quad * 4 + t;
                    float x0o = x[40 + u];
                    F[24 + u] = x0o * A_VEC;  // wD1e
                    F[44 + u] = x0o * c0S;    // wD0o
                }
            }
        }

        // ---- GEMM1 (crew0 only): H[e][hid] -> sH ----
        if (half == 0) {
            f32x4 c0 = {0.f,0.f,0.f,0.f}, c1 = {0.f,0.f,0.f,0.f}, c2 = {0.f,0.f,0.f,0.f};
            c0 = __builtin_amdgcn_mfma_f32_16x16x32_bf16(a00, hb0, c0, 0, 0, 0);
            c0 = __builtin_amdgcn_mfma_f32_16x16x32_bf16(a01, hb1, c0, 0, 0, 0);
            c1 = __builtin_amdgcn_mfma_f32_16x16x32_bf16(a10, hb0, c1, 0, 0, 0);
            c1 = __builtin_amdgcn_mfma_f32_16x16x32_bf16(a11, hb1, c1, 0, 0, 0);
            c2 = __builtin_amdgcn_mfma_f32_16x16x32_bf16(a20, hb0, c2, 0, 0, 0);
            c2 = __builtin_amdgcn_mfma_f32_16x16x32_bf16(a21, hb1, c2, 0, 0, 0);
            u16x4 h0, h1, h2;
            #pragma unroll
            for (int r = 0; r < 4; r++) {
                h0[r] = f2bf(fmaxf(c0[r], 0.f));
                h1[r] = f2bf(fmaxf(c1[r], 0.f));
                h2[r] = f2bf(fmaxf(c2[r], 0.f));
            }
            *(u16x4*)&sH[em * 72 +  0 + quad*4] = h0;
            *(u16x4*)&sH[em * 72 + 16 + quad*4] = h1;
            *(u16x4*)&sH[em * 72 + 32 + quad*4] = h2;
            if (quad == 3) {
                u16x4 b = {0x3F80, 0, 0, 0}, z = {0, 0, 0, 0};
                *(u16x4*)&sH[em * 72 + 48] = b;
                *(u16x4*)&sH[em * 72 + 52] = z;
                *(u16x4*)&sH[em * 72 + 56] = z;
                *(u16x4*)&sH[em * 72 + 60] = z;
            }
        }
        __syncthreads();   // (D) sH visible to all waves

        bf16x8 HB0 = __builtin_bit_cast(bf16x8, *(const u16x8*)&sH[em * 72 + quad*8]);
        bf16x8 HB1 = __builtin_bit_cast(bf16x8, *(const u16x8*)&sH[em * 72 + 32 + quad*8]);

        // ---- issue next task's front-end loads (latency hides under GEMM2) ----
        {
            int nt_ = task + STRIDE;
            PREFETCH(nt_ < NTASK ? nt_ : task);
        }

        const unsigned short* Wt = W2L + (size_t)half * 26 * 1024;  // global, L2-hot

        if (half == 0) {
            const float* Fp = sF0 + em * 61;
            // ---- tiles 0..25: o0e (ch 0..15) + o1o (ch 16..27) ----
            float oe[4] = {0.f,0.f,0.f,0.f};
            float sA[4] = {0.f,0.f,0.f,0.f};
            float t1[12] = {0.f,0.f,0.f,0.f,0.f,0.f,0.f,0.f,0.f,0.f,0.f,0.f};
            #pragma unroll
            for (int i = 0; i < 26; i++) {
                u16x8 Af = *(const u16x8*)&Wt[i * 1024 + lane * 8];
                u16x8 Bf = *(const u16x8*)&Wt[i * 1024 + 512 + lane * 8];
                f32x4 c = {0.f,0.f,0.f,0.f};
                c = __builtin_amdgcn_mfma_f32_16x16x32_bf16(__builtin_bit_cast(bf16x8, Af), HB0, c, 0, 0, 0);
                c = __builtin_amdgcn_mfma_f32_16x16x32_bf16(__builtin_bit_cast(bf16x8, Bf), HB1, c, 0, 0, 0);
                if (i < 20) {
                    float f = Fp[i];
                    #pragma unroll
                    for (int r = 0; r < 4; r++) oe[r] += f * c[r];
                } else if (i < 24) {
                    float f = Fp[20 + (i - 20)*4 + quad];
                    #pragma unroll
                    for (int r = 0; r < 4; r++) sA[r] += f * c[r];
                } else {
                    int u = (i - 24)*4 + quad;
                    #pragma unroll
                    for (int i3 = 0; i3 < 3; i3++) {
                        float f = Fp[36 + u*3 + i3];
                        #pragma unroll
                        for (int r = 0; r < 4; r++) t1[i3*4 + r] += f * c[r];
                    }
                }
            }
            #pragma unroll
            for (int r = 0; r < 4; r++) {
                sA[r] += __shfl_xor(sA[r], 16, 64);  sA[r] += __shfl_xor(sA[r], 32, 64);
            }
            #pragma unroll
            for (int i = 0; i < 12; i++) {
                t1[i] += __shfl_xor(t1[i], 16, 64);  t1[i] += __shfl_xor(t1[i], 32, 64);
            }
            float4 v0; v0.x = oe[0]; v0.y = oe[1]; v0.z = oe[2]; v0.w = oe[3];
            *(float4*)&sO[em * IRR + quad*4] = v0;                 // ch 0..15
            if (quad == 0) {
                #pragma unroll
                for (int r = 0; r < 4; r++) {
                    sO[em * IRR + 16 + r*3 + 0] = sA[r] * sx + t1[0*4 + r];
                    sO[em * IRR + 16 + r*3 + 1] = sA[r] * sy + t1[1*4 + r];
                    sO[em * IRR + 16 + r*3 + 2] = sA[r] * sz + t1[2*4 + r];
                }
            }
        } else {
            const float* Fp = sF1 + em * 61;
            // ---- tiles 26..51: o1e (ch 28..39) + o0o (ch 40..55) ----
            float sD[4] = {0.f,0.f,0.f,0.f};
            float t1[12] = {0.f,0.f,0.f,0.f,0.f,0.f,0.f,0.f,0.f,0.f,0.f,0.f};
            float oo[4] = {0.f,0.f,0.f,0.f};
            #pragma unroll
            for (int i = 0; i < 26; i++) {
                u16x8 Af = *(const u16x8*)&Wt[i * 1024 + lane * 8];
                u16x8 Bf = *(const u16x8*)&Wt[i * 1024 + 512 + lane * 8];
                f32x4 c = {0.f,0.f,0.f,0.f};
                c = __builtin_amdgcn_mfma_f32_16x16x32_bf16(__builtin_bit_cast(bf16x8, Af), HB0, c, 0, 0, 0);
                c = __builtin_amdgcn_mfma_f32_16x16x32_bf16(__builtin_bit_cast(bf16x8, Bf), HB1, c, 0, 0, 0);
                if (i < 2) {
                    int j = i*4 + quad;
                    #pragma unroll
                    for (int i3 = 0; i3 < 3; i3++) {
                        float f = Fp[j*3 + i3];
                        #pragma unroll
                        for (int r = 0; r < 4; r++) t1[i3*4 + r] += f * c[r];
                    }
                } else if (i < 6) {
                    float f = Fp[24 + (i - 2)*4 + quad];
                    #pragma unroll
                    for (int r = 0; r < 4; r++) sD[r] += f * c[r];
                } else {
                    float f = Fp[40 + (i - 6)];
                    #pragma unroll
                    for (int r = 0; r < 4; r++) oo[r] += f * c[r];
                }
            }
            #pragma unroll
            for (int r = 0; r < 4; r++) {
                sD[r] += __shfl_xor(sD[r], 16, 64);  sD[r] += __shfl_xor(sD[r], 32, 64);
            }
            #pragma unroll
            for (int i = 0; i < 12; i++) {
                t1[i] += __shfl_xor(t1[i], 16, 64);  t1[i] += __shfl_xor(t1[i], 32, 64);
            }
            float4 v1; v1.x = oo[0]; v1.y = oo[1]; v1.z = oo[2]; v1.w = oo[3];
            *(float4*)&sO[em * IRR + 28 + 12 + quad*4] = v1;      // ch 40..55
            if (quad == 0) {
                #pragma unroll
                for (int r = 0; r < 4; r++) {                     // ch 28..39
                    sO[em * IRR + 28 + r*3 + 0] = sD[r] * sx + t1[0*4 + r];
                    sO[em * IRR + 28 + r*3 + 1] = sD[r] * sy + t1[1*4 + r];
                    sO[em * IRR + 28 + r*3 + 2] = sD[r] * sz + t1[2*4 + r];
                }
            }
        }

        __syncthreads();   // (E) sO complete block-wide (also drains prefetch loads)

        // ---- pre-scaled atomic scatter: full contiguous 224 B rows per edge ----
        #pragma unroll
        for (int it = 0; it < 7; it++) {
            int idx = it * NT + tid;           // < 3584 = 64*56
            int e = idx / IRR, ch = idx - e * IRR;
            unsafeAtomicAdd(&out[(size_t)sSrc[e] * IRR + ch], sO[e * IRR + ch] * sInv[e]);
        }
    }
}

extern "C" void kernel_launch(void* const* d_in, const int* in_sizes, int n_in,
                              void* d_out, int out_size, void* d_ws, size_t ws_size,
                              hipStream_t stream) {
    const float* node_attr  = (const float*)d_in[0];
    const float* edge_attr  = (const float*)d_in[1];
    const float* edge_sh    = (const float*)d_in[2];
    const float* fc_w1      = (const float*)d_in[3];
    const float* fc_b1      = (const float*)d_in[4];
    const float* fc_w2      = (const float*)d_in[5];
    const float* fc_b2      = (const float*)d_in[6];
    const int*   edge_index = (const int*)d_in[7];

    int* hist = (int*)d_ws;                                    // 8000 ints
    unsigned short* W1T = (unsigned short*)(hist + NNODE);     // 48*64
    unsigned short* W2L = W1T + EF * 64;                       // 52*2*64*8 = 53248

    hipMemsetAsync(hist, 0, NNODE * sizeof(int), stream);
    hipMemsetAsync(d_out, 0, (size_t)out_size * sizeof(float), stream);

    k_setup<<<(NEDGE + 255) / 256, 256, 0, stream>>>(
        fc_w1, fc_b1, fc_w2, fc_b2, W1T, W2L, edge_index, hist);

    tp_fused<<<GRID, NT, 0, stream>>>(node_attr, edge_attr, edge_sh, edge_index,
                                      hist, W1T, W2L, (float*)d_out);
}